// Round 1
// baseline (617.294 us; speedup 1.0000x reference)
//
#include <hip/hip_runtime.h>

#define CPG 8
#define NGRP 32
#define NB 16
#define HW 3136      // 56*56
#define HW2 1568     // HW in float2 units
#define N2 36
#define N3 120

// index of pair (i,j), i<=j, in np.triu_indices(8) lexicographic order
__host__ __device__ constexpr int idx2(int i, int j) {
    return i * CPG - i * (i - 1) / 2 + (j - i);
}
// index of triple (a,b,c), a<=b<=c, in reference lexicographic order
__host__ __device__ constexpr int idx3(int a, int b, int c) {
    int base = 0;
    for (int i = 0; i < a; ++i) { int m = CPG - i; base += m * (m + 1) / 2; }
    for (int j = a; j < b; ++j) base += CPG - j;
    return base + (c - b);
}

__global__ __launch_bounds__(256, 4) void hoaf_kernel(
    const float* __restrict__ x,
    const float* __restrict__ w1, const float* __restrict__ b1,
    const float* __restrict__ w2, const float* __restrict__ b2,
    const float* __restrict__ w3, const float* __restrict__ b3,
    float* __restrict__ out)
{
    const int tid   = threadIdx.x;
    const int chunk = blockIdx.x;   // 0..1
    const int g     = blockIdx.y;   // block-uniform group -> scalar weight loads
    const int b     = blockIdx.z;

    const float* wg1 = w1 + g * CPG * CPG;   // [o][k]
    const float* wg2 = w2 + g * CPG * N2;    // [o][pair]
    const float* wg3 = w3 + g * CPG * N3;    // [o][triple]

    float bias[CPG];
#pragma unroll
    for (int o = 0; o < CPG; ++o)
        bias[o] = b1[g * CPG + o] + b2[g * CPG + o] + b3[g * CPG + o];

    const size_t base = ((size_t)(b * NGRP + g) * CPG) * HW;
    const float2* x2 = (const float2*)(x + base);
    float2*       o2 = (float2*)(out + base);

    for (int q = tid + chunk * 256; q < HW2; q += 512) {
        float2 xv[CPG];
#pragma unroll
        for (int ch = 0; ch < CPG; ++ch) xv[ch] = x2[(size_t)ch * HW2 + q];

        float2 acc[CPG];
#pragma unroll
        for (int o = 0; o < CPG; ++o) { acc[o].x = bias[o]; acc[o].y = bias[o]; }

        // degree 1: out_o += sum_k w1[o][k] * x_k
#pragma unroll
        for (int k = 0; k < CPG; ++k) {
#pragma unroll
            for (int o = 0; o < CPG; ++o) {
                const float w = wg1[o * CPG + k];
                acc[o].x += w * xv[k].x;
                acc[o].y += w * xv[k].y;
            }
        }

        // degree 2 & 3 interleaved: pair (i<=j) product feeds triples (a<=i<=j)
#pragma unroll
        for (int i = 0; i < CPG; ++i) {
#pragma unroll
            for (int j = i; j < CPG; ++j) {
                float2 p;
                p.x = xv[i].x * xv[j].x;
                p.y = xv[i].y * xv[j].y;
                const int p2 = idx2(i, j);
#pragma unroll
                for (int o = 0; o < CPG; ++o) {
                    const float w = wg2[o * N2 + p2];
                    acc[o].x += w * p.x;
                    acc[o].y += w * p.y;
                }
#pragma unroll
                for (int a = 0; a <= i; ++a) {
                    float2 t;
                    t.x = xv[a].x * p.x;
                    t.y = xv[a].y * p.y;
                    const int p3 = idx3(a, i, j);
#pragma unroll
                    for (int o = 0; o < CPG; ++o) {
                        const float w = wg3[o * N3 + p3];
                        acc[o].x += w * t.x;
                        acc[o].y += w * t.y;
                    }
                }
            }
        }

#pragma unroll
        for (int o = 0; o < CPG; ++o) o2[(size_t)o * HW2 + q] = acc[o];
    }
}

extern "C" void kernel_launch(void* const* d_in, const int* in_sizes, int n_in,
                              void* d_out, int out_size, void* d_ws, size_t ws_size,
                              hipStream_t stream) {
    const float* x  = (const float*)d_in[0];
    const float* w1 = (const float*)d_in[1];
    const float* b1 = (const float*)d_in[2];
    const float* w2 = (const float*)d_in[3];
    const float* b2 = (const float*)d_in[4];
    const float* w3 = (const float*)d_in[5];
    const float* b3 = (const float*)d_in[6];
    float* out = (float*)d_out;

    dim3 grid(2, NGRP, NB);
    dim3 block(256);
    hoaf_kernel<<<grid, block, 0, stream>>>(x, w1, b1, w2, b2, w3, b3, out);
}